// Round 1
// baseline (205.004 us; speedup 1.0000x reference)
//
#include <hip/hip_runtime.h>
#include <hip/hip_bf16.h>

// S4 layer: y = irfft( rfft(pad(u)) * (rfft(pad(K)) + D) )[:L]
//   K[h] = Re(ifft_L(atRoots[h])),  atRoots from DPLR resolvent (rescaled form).
// B=16, H=128, L=4096, N=64. All fp32.
// ws layout: [0, 4MB)   atRoots : 128 x 4096 float2
//            [4MB, ~8.4MB) Khat : 128 x 4097 float2   (needs ws_size >= 8.4 MB)

#define PI_F 3.14159265358979323846f

__device__ __forceinline__ int sw_(int i) { return i ^ ((i >> 4) & 15); }

__device__ __forceinline__ float2 cmulf(float2 a, float2 b) {
  return make_float2(a.x * b.x - a.y * b.y, a.x * b.y + a.y * b.x);
}

// ---------------- Kernel 1a: Cauchy sums -> atRoots ----------------
// Rescaled (singularity-free) form:
//   t = (1+Om)/2, q = (1-Om)/step, s_n = 1/(q - t*Lam_n), S_ij = sum V_ij*s_n
//   atRoots = S00 - t*S01*S10/(1 + t*S11)
__global__ __launch_bounds__(256) void k_cauchy(
    const float* __restrict__ Lre, const float* __restrict__ Lim,
    const float* __restrict__ Pri, const float* __restrict__ Bri,
    const float* __restrict__ Cri, const float* __restrict__ lstep,
    float2* __restrict__ atR) {
  __shared__ float4 pA[64];  // v00r v00i v01r v01i
  __shared__ float4 pB[64];  // v10r v10i v11r 0
  __shared__ float2 pL[64];  // lam_re lam_im
  const int h = blockIdx.x >> 2;
  const int sub = blockIdx.x & 3;
  const int tid = threadIdx.x;
  if (tid < 64) {
    int n = tid;
    int base = h * 64 + n;
    float lr = fminf(Lre[base], -1e-4f);
    float li = Lim[base];
    float pr = Pri[2 * base], pi = Pri[2 * base + 1];
    float br = Bri[2 * base], bi = Bri[2 * base + 1];
    float cr = Cri[2 * base], ci = Cri[2 * base + 1];
    // V00 = conj(C)*B, V01 = conj(C)*P, V10 = conj(P)*B, V11 = |P|^2 (real)
    pA[n] = make_float4(cr * br + ci * bi, cr * bi - ci * br,
                        cr * pr + ci * pi, cr * pi - ci * pr);
    pB[n] = make_float4(pr * br + pi * bi, pr * bi - pi * br,
                        pr * pr + pi * pi, 0.f);
    pL[n] = make_float2(lr, li);
  }
  __syncthreads();
  const float step = expf(lstep[h]);
  const float istep = 1.0f / step;

  float trm[4], tim[4], qrm[4], qim[4];
#pragma unroll
  for (int i = 0; i < 4; ++i) {
    int m = sub * 1024 + i * 256 + tid;
    float ang = -(2.0f * PI_F / 4096.0f) * (float)m;
    float sn, cn;
    __sincosf(ang, &sn, &cn);
    trm[i] = 0.5f * (1.0f + cn);
    tim[i] = 0.5f * sn;
    qrm[i] = (1.0f - cn) * istep;
    qim[i] = -sn * istep;
  }
  float S[4][8];
#pragma unroll
  for (int i = 0; i < 4; ++i)
#pragma unroll
    for (int jj = 0; jj < 8; ++jj) S[i][jj] = 0.f;

#pragma unroll 4
  for (int n = 0; n < 64; ++n) {
    float4 a = pA[n];
    float4 b = pB[n];
    float2 L = pL[n];
#pragma unroll
    for (int i = 0; i < 4; ++i) {
      float dr = qrm[i] - (trm[i] * L.x - tim[i] * L.y);
      float di = qim[i] - (trm[i] * L.y + tim[i] * L.x);
      float inv = __builtin_amdgcn_rcpf(dr * dr + di * di);
      float sr = dr * inv, si = -di * inv;
      S[i][0] += a.x * sr - a.y * si;  S[i][1] += a.x * si + a.y * sr;
      S[i][2] += a.z * sr - a.w * si;  S[i][3] += a.z * si + a.w * sr;
      S[i][4] += b.x * sr - b.y * si;  S[i][5] += b.x * si + b.y * sr;
      S[i][6] += b.z * sr;             S[i][7] += b.z * si;
    }
  }
#pragma unroll
  for (int i = 0; i < 4; ++i) {
    int m = sub * 1024 + i * 256 + tid;
    float tS11r = trm[i] * S[i][6] - tim[i] * S[i][7];
    float tS11i = trm[i] * S[i][7] + tim[i] * S[i][6];
    float denr = 1.0f + tS11r, deni = tS11i;
    float dinv = 1.0f / (denr * denr + deni * deni);
    float P1r = S[i][2] * S[i][4] - S[i][3] * S[i][5];
    float P1i = S[i][2] * S[i][5] + S[i][3] * S[i][4];
    float P2r = trm[i] * P1r - tim[i] * P1i;
    float P2i = trm[i] * P1i + tim[i] * P1r;
    float Qr = (P2r * denr + P2i * deni) * dinv;
    float Qi = (P2i * denr - P2r * deni) * dinv;
    atR[h * 4096 + m] = make_float2(S[i][0] - Qr, S[i][1] - Qi);
  }
}

// ---------------- Radix-4 Stockham FFT, 4096 pts, in LDS ----------------
// SIGN=-1 forward (e^{-i}), SIGN=+1 inverse (unnormalized).
template <int SIGN>
__device__ __forceinline__ void fft_stage(const float2* __restrict__ src,
                                          float2* __restrict__ dst, int ls,
                                          int tid) {
  const float TH = (float)SIGN * (2.0f * PI_F / 4096.0f);
  const int s = 1 << ls;
#pragma unroll
  for (int it = 0; it < 4; ++it) {
    const int j = tid + it * 256;
    const int q = j & (s - 1);
    const int pb = j - q;  // p*s, in [0,1024)
    float sn, cn;
    __sincosf(TH * (float)pb, &sn, &cn);
    const float2 w1 = make_float2(cn, sn);
    const float2 w2 = cmulf(w1, w1);
    const float2 w3 = cmulf(w2, w1);
    const float2 a = src[sw_(j)];
    const float2 b = src[sw_(j + 1024)];
    const float2 c = src[sw_(j + 2048)];
    const float2 d = src[sw_(j + 3072)];
    const float apcx = a.x + c.x, apcy = a.y + c.y;
    const float amcx = a.x - c.x, amcy = a.y - c.y;
    const float bpdx = b.x + d.x, bpdy = b.y + d.y;
    const float bmdx = b.x - d.x, bmdy = b.y - d.y;
    float2 o1, o3;
    if (SIGN < 0) {  // out1 = amc - i*bmd ; out3 = amc + i*bmd
      o1 = make_float2(amcx + bmdy, amcy - bmdx);
      o3 = make_float2(amcx - bmdy, amcy + bmdx);
    } else {
      o1 = make_float2(amcx - bmdy, amcy + bmdx);
      o3 = make_float2(amcx + bmdy, amcy - bmdx);
    }
    const int wb = (pb << 2) + q;
    dst[sw_(wb)] = make_float2(apcx + bpdx, apcy + bpdy);
    dst[sw_(wb + s)] = cmulf(w1, o1);
    dst[sw_(wb + 2 * s)] = cmulf(w2, make_float2(apcx - bpdx, apcy - bpdy));
    dst[sw_(wb + 3 * s)] = cmulf(w3, o3);
  }
}

template <int SIGN>
__device__ void fft4096(float2* x, float2* y, int tid) {
  fft_stage<SIGN>(x, y, 0, tid);  __syncthreads();
  fft_stage<SIGN>(y, x, 2, tid);  __syncthreads();
  fft_stage<SIGN>(x, y, 4, tid);  __syncthreads();
  fft_stage<SIGN>(y, x, 6, tid);  __syncthreads();
  fft_stage<SIGN>(x, y, 8, tid);  __syncthreads();
  fft_stage<SIGN>(y, x, 10, tid); __syncthreads();
  // result in x, natural order
}

// ---------------- Kernel 1b: atRoots -> Khat (+D) ----------------
__global__ __launch_bounds__(256) void k_khat(const float2* __restrict__ atR,
                                              const float* __restrict__ Dp,
                                              float2* __restrict__ Khat) {
  __shared__ float2 bufA[4096];
  __shared__ float2 bufB[4096];
  const int h = blockIdx.x;
  const int tid = threadIdx.x;
  for (int i = tid; i < 4096; i += 256) bufA[sw_(i)] = atR[h * 4096 + i];
  __syncthreads();
  fft4096<1>(bufA, bufB, tid);  // unnormalized inverse; result in bufA
  const float s = 1.0f / 4096.0f;
  // K[l] = Re(zK[l])/4096 ; pack K[2n]+iK[2n+1], zero-pad to 2L
  for (int nn = tid; nn < 2048; nn += 256)
    bufB[sw_(nn)] =
        make_float2(bufA[sw_(2 * nn)].x * s, bufA[sw_(2 * nn + 1)].x * s);
  for (int nn = 2048 + tid; nn < 4096; nn += 256)
    bufB[sw_(nn)] = make_float2(0.f, 0.f);
  __syncthreads();
  fft4096<-1>(bufB, bufA, tid);  // forward; result in bufB
  const float Dh = Dp[h];
  float2* Kr = Khat + h * 4097;
  for (int k = tid; k <= 2048; k += 256) {
    float2 Zk = bufB[sw_(k)];
    float2 Zm = bufB[sw_((4096 - k) & 4095)];
    float Er = 0.5f * (Zk.x + Zm.x), Ei = 0.5f * (Zk.y - Zm.y);
    float Or = 0.5f * (Zk.y + Zm.y), Oi = 0.5f * (Zm.x - Zk.x);
    float swn, cwn;
    __sincosf(-(PI_F / 4096.0f) * (float)k, &swn, &cwn);
    float WOr = cwn * Or - swn * Oi, WOi = cwn * Oi + swn * Or;
    Kr[k] = make_float2(Er + WOr + Dh, Ei + WOi);  // + D folded in (DC delta)
    if (k != 2048) Kr[4096 - k] = make_float2(Er - WOr + Dh, WOi - Ei);
  }
}

// ---------------- Kernel 2: per-row FFT convolution ----------------
__global__ __launch_bounds__(256) void k_conv(const float* __restrict__ u,
                                              const float2* __restrict__ Khat,
                                              float* __restrict__ y) {
  __shared__ float2 bufA[4096];
  __shared__ float2 bufB[4096];
  const int r = blockIdx.x;  // b*128 + h
  const int h = r & 127;
  const int tid = threadIdx.x;
  const float4* u4 = (const float4*)(u + (size_t)r * 4096);
#pragma unroll
  for (int i = 0; i < 4; ++i) {
    int j4 = tid + i * 256;
    float4 v = u4[j4];
    bufA[sw_(2 * j4)] = make_float2(v.x, v.y);
    bufA[sw_(2 * j4 + 1)] = make_float2(v.z, v.w);
  }
  for (int nn = 2048 + tid; nn < 4096; nn += 256)
    bufA[sw_(nn)] = make_float2(0.f, 0.f);
  __syncthreads();
  fft4096<-1>(bufA, bufB, tid);  // forward; Z in bufA
  const float2* __restrict__ Kr = Khat + h * 4097;
  const float s = 1.0f / 4096.0f;
  // untangle rfft bins, multiply, retangle for inverse (with 1/4096 folded)
  for (int k = tid; k <= 2048; k += 256) {
    float2 Zk = bufA[sw_(k)];
    float2 Zm = bufA[sw_((4096 - k) & 4095)];
    float Er = 0.5f * (Zk.x + Zm.x), Ei = 0.5f * (Zk.y - Zm.y);
    float Or = 0.5f * (Zk.y + Zm.y), Oi = 0.5f * (Zm.x - Zk.x);
    float swn, cwn;
    __sincosf(-(PI_F / 4096.0f) * (float)k, &swn, &cwn);
    float WOr = cwn * Or - swn * Oi, WOi = cwn * Oi + swn * Or;
    float U1r = Er + WOr, U1i = Ei + WOi;   // Uhat[k]
    float U2r = Er - WOr, U2i = WOi - Ei;   // Uhat[4096-k]
    float2 K1 = Kr[k], K2 = Kr[4096 - k];
    float Y1r = U1r * K1.x - U1i * K1.y, Y1i = U1r * K1.y + U1i * K1.x;
    float Y2r = U2r * K2.x - U2i * K2.y, Y2i = U2r * K2.y + U2i * K2.x;
    float Epr = 0.5f * (Y1r + Y2r), Epi = 0.5f * (Y1i - Y2i);
    float Tr = 0.5f * (Y1r - Y2r), Ti = 0.5f * (Y1i + Y2i);
    float O2r = cwn * Tr + swn * Ti, O2i = cwn * Ti - swn * Tr;  // conj(W)*T
    bufB[sw_(k)] = make_float2((Epr - O2i) * s, (Epi + O2r) * s);
    if (k != 0 && k != 2048)
      bufB[sw_(4096 - k)] = make_float2((Epr + O2i) * s, (O2r - Epi) * s);
  }
  __syncthreads();
  fft4096<1>(bufB, bufA, tid);  // inverse; zy in bufB (already /4096)
  float4* y4 = (float4*)(y + (size_t)r * 4096);
#pragma unroll
  for (int i = 0; i < 4; ++i) {
    int j4 = tid + i * 256;
    float2 z0 = bufB[sw_(2 * j4)];
    float2 z1 = bufB[sw_(2 * j4 + 1)];
    y4[j4] = make_float4(z0.x, z0.y, z1.x, z1.y);
  }
}

extern "C" void kernel_launch(void* const* d_in, const int* in_sizes, int n_in,
                              void* d_out, int out_size, void* d_ws,
                              size_t ws_size, hipStream_t stream) {
  (void)in_sizes; (void)n_in; (void)out_size; (void)ws_size;
  const float* u = (const float*)d_in[0];
  const float* Lre = (const float*)d_in[1];
  const float* Lim = (const float*)d_in[2];
  const float* Pri = (const float*)d_in[3];
  const float* Bri = (const float*)d_in[4];
  const float* Cri = (const float*)d_in[5];
  const float* lst = (const float*)d_in[6];
  const float* Dp = (const float*)d_in[7];
  float* y = (float*)d_out;
  float2* atR = (float2*)d_ws;
  float2* Khat = (float2*)((char*)d_ws + (size_t)128 * 4096 * sizeof(float2));

  k_cauchy<<<512, 256, 0, stream>>>(Lre, Lim, Pri, Bri, Cri, lst, atR);
  k_khat<<<128, 256, 0, stream>>>(atR, Dp, Khat);
  k_conv<<<2048, 256, 0, stream>>>(u, Khat, y);
}

// Round 2
// 160.034 us; speedup vs baseline: 1.2810x; 1.2810x over previous
//
#include <hip/hip_runtime.h>
#include <hip/hip_bf16.h>

// S4 layer: y = irfft( rfft(pad(u)) * (rfft(pad(K)) + D) )[:L]
// B=16, H=128, L=4096, N=64. All fp32.
// FFT4096 = 16^3 register FFT: 3x in-register FFT16 + 2 LDS transposes.
// LDS: single 4368-float2 buffer (34.9 KB) -> 4 blocks/CU.
// ws layout: [0,4MB) atRoots 128x4096 float2 ; [4MB,..) Khat 128x4097 float2

#define PI_F 3.14159265358979323846f

__device__ __forceinline__ float2 cmulf(float2 a, float2 b) {
  return make_float2(a.x * b.x - a.y * b.y, a.x * b.y + a.y * b.x);
}
__device__ __forceinline__ void cmul_set(float2& v, float wr, float wi) {
  v = make_float2(v.x * wr - v.y * wi, v.x * wi + v.y * wr);
}
__device__ __forceinline__ int ad(int k) { return k + (k >> 4); }  // nat+pad

// radix-4 butterfly, in place. SIGN=-1 forward (e^{-i}), +1 inverse.
template <int SIGN>
__device__ __forceinline__ void bfly4(float2& a, float2& b, float2& c,
                                      float2& d) {
  float t0x = a.x + c.x, t0y = a.y + c.y;
  float t1x = a.x - c.x, t1y = a.y - c.y;
  float t2x = b.x + d.x, t2y = b.y + d.y;
  float t3x = b.x - d.x, t3y = b.y - d.y;
  a = make_float2(t0x + t2x, t0y + t2y);
  c = make_float2(t0x - t2x, t0y - t2y);
  if (SIGN < 0) {  // X1 = t1 - i*t3 ; X3 = t1 + i*t3
    b = make_float2(t1x + t3y, t1y - t3x);
    d = make_float2(t1x - t3y, t1y + t3x);
  } else {
    b = make_float2(t1x - t3y, t1y + t3x);
    d = make_float2(t1x + t3y, t1y - t3x);
  }
}

// in-register 16-point FFT, natural in / natural out. All twiddles constant.
template <int SIGN>
__device__ __forceinline__ void fft16(float2 v[16]) {
  const float sg = (float)SIGN;
  const float C1 = 0.92387953251128674f;  // cos(pi/8)
  const float S1 = 0.38268343236508978f;  // sin(pi/8)
  const float R2 = 0.70710678118654752f;
  // stage 1: FFT4 over n1 (stride 4); slot n0+4g holds Y[n0][g]
  bfly4<SIGN>(v[0], v[4], v[8], v[12]);
  bfly4<SIGN>(v[1], v[5], v[9], v[13]);
  bfly4<SIGN>(v[2], v[6], v[10], v[14]);
  bfly4<SIGN>(v[3], v[7], v[11], v[15]);
  // twiddle w16^{n0*g} = (cos(2pi e/16), sg*sin(2pi e/16))
  cmul_set(v[5], C1, sg * S1);                   // e=1
  cmul_set(v[6], R2, sg * R2);                   // e=2
  cmul_set(v[7], S1, sg * C1);                   // e=3
  cmul_set(v[9], R2, sg * R2);                   // e=2
  v[10] = make_float2(-sg * v[10].y, sg * v[10].x);  // e=4 -> (0, sg)
  cmul_set(v[11], -R2, sg * R2);                 // e=6
  cmul_set(v[13], S1, sg * C1);                  // e=3
  cmul_set(v[14], -R2, sg * R2);                 // e=6
  cmul_set(v[15], -C1, -sg * S1);                // e=9
  // stage 2: FFT4 over n0 within group g; output k = g + 4m
  float2 w[16];
#pragma unroll
  for (int g = 0; g < 4; ++g) {
    float2 x0 = v[4 * g], x1 = v[4 * g + 1], x2 = v[4 * g + 2],
           x3 = v[4 * g + 3];
    bfly4<SIGN>(x0, x1, x2, x3);
    w[g] = x0; w[g + 4] = x1; w[g + 8] = x2; w[g + 12] = x3;
  }
#pragma unroll
  for (int i = 0; i < 16; ++i) v[i] = w[i];
}

// 4096-pt FFT. In: v[c] = x[tid + 256c]. Out: v[al] = X[(tid>>4) + 16*(tid&15) + 256*al].
// Uses lds[0..4365]; caller must barrier before reusing lds afterwards.
template <int SIGN>
__device__ void fft4096_regs(float2 v[16], float2* lds, int tid) {
  const float TH1 = (float)SIGN * (2.0f * PI_F / 4096.0f);
  const float TH2 = (float)SIGN * (2.0f * PI_F / 256.0f);
  fft16<SIGN>(v);  // over c
  {
    float sn, cn;
    __sincosf(TH1 * (float)tid, &sn, &cn);
    float2 w1 = make_float2(cn, sn), cw = w1;
#pragma unroll
    for (int g = 1; g < 16; ++g) {
      v[g] = cmulf(v[g], cw);
      if (g < 15) cw = cmulf(cw, w1);
    }
  }
  __syncthreads();  // protect caller's prior LDS reads
#pragma unroll
  for (int g = 0; g < 16; ++g) lds[tid * 17 + g] = v[g];
  __syncthreads();
  const int a = tid & 15, g2 = tid >> 4;
#pragma unroll
  for (int b = 0; b < 16; ++b) v[b] = lds[a * 17 + b * 272 + g2];
  fft16<SIGN>(v);  // over b
  {
    float sn, cn;
    __sincosf(TH2 * (float)a, &sn, &cn);
    float2 w1 = make_float2(cn, sn), cw = w1;
#pragma unroll
    for (int b = 1; b < 16; ++b) {
      v[b] = cmulf(v[b], cw);
      if (b < 15) cw = cmulf(cw, w1);
    }
  }
  __syncthreads();
#pragma unroll
  for (int b = 0; b < 16; ++b) lds[g2 * 17 + b * 273 + a] = v[b];
  __syncthreads();
#pragma unroll
  for (int a2 = 0; a2 < 16; ++a2) v[a2] = lds[g2 * 17 + a * 273 + a2];
  fft16<SIGN>(v);  // over a
}

// ---------------- Kernel 1a: Cauchy sums -> atRoots ----------------
__global__ __launch_bounds__(256) void k_cauchy(
    const float* __restrict__ Lre, const float* __restrict__ Lim,
    const float* __restrict__ Pri, const float* __restrict__ Bri,
    const float* __restrict__ Cri, const float* __restrict__ lstep,
    float2* __restrict__ atR) {
  __shared__ float4 pA[64];
  __shared__ float4 pB[64];
  __shared__ float2 pL[64];
  const int h = blockIdx.x >> 2;
  const int sub = blockIdx.x & 3;
  const int tid = threadIdx.x;
  if (tid < 64) {
    int n = tid;
    int base = h * 64 + n;
    float lr = fminf(Lre[base], -1e-4f);
    float li = Lim[base];
    float pr = Pri[2 * base], pi = Pri[2 * base + 1];
    float br = Bri[2 * base], bi = Bri[2 * base + 1];
    float cr = Cri[2 * base], ci = Cri[2 * base + 1];
    pA[n] = make_float4(cr * br + ci * bi, cr * bi - ci * br,
                        cr * pr + ci * pi, cr * pi - ci * pr);
    pB[n] = make_float4(pr * br + pi * bi, pr * bi - pi * br,
                        pr * pr + pi * pi, 0.f);
    pL[n] = make_float2(lr, li);
  }
  __syncthreads();
  const float istep = expf(-lstep[h]);

  float trm[4], tim[4], qrm[4], qim[4];
#pragma unroll
  for (int i = 0; i < 4; ++i) {
    int m = sub * 1024 + i * 256 + tid;
    float ang = -(2.0f * PI_F / 4096.0f) * (float)m;
    float sn, cn;
    __sincosf(ang, &sn, &cn);
    trm[i] = 0.5f * (1.0f + cn);
    tim[i] = 0.5f * sn;
    qrm[i] = (1.0f - cn) * istep;
    qim[i] = -sn * istep;
  }
  float S[4][8];
#pragma unroll
  for (int i = 0; i < 4; ++i)
#pragma unroll
    for (int jj = 0; jj < 8; ++jj) S[i][jj] = 0.f;

#pragma unroll 4
  for (int n = 0; n < 64; ++n) {
    float4 a = pA[n];
    float4 b = pB[n];
    float2 L = pL[n];
#pragma unroll
    for (int i = 0; i < 4; ++i) {
      float dr = qrm[i] - (trm[i] * L.x - tim[i] * L.y);
      float di = qim[i] - (trm[i] * L.y + tim[i] * L.x);
      float inv = __builtin_amdgcn_rcpf(dr * dr + di * di);
      float sr = dr * inv, si = -di * inv;
      S[i][0] += a.x * sr - a.y * si;  S[i][1] += a.x * si + a.y * sr;
      S[i][2] += a.z * sr - a.w * si;  S[i][3] += a.z * si + a.w * sr;
      S[i][4] += b.x * sr - b.y * si;  S[i][5] += b.x * si + b.y * sr;
      S[i][6] += b.z * sr;             S[i][7] += b.z * si;
    }
  }
#pragma unroll
  for (int i = 0; i < 4; ++i) {
    int m = sub * 1024 + i * 256 + tid;
    float tS11r = trm[i] * S[i][6] - tim[i] * S[i][7];
    float tS11i = trm[i] * S[i][7] + tim[i] * S[i][6];
    float denr = 1.0f + tS11r, deni = tS11i;
    float dinv = 1.0f / (denr * denr + deni * deni);
    float P1r = S[i][2] * S[i][4] - S[i][3] * S[i][5];
    float P1i = S[i][2] * S[i][5] + S[i][3] * S[i][4];
    float P2r = trm[i] * P1r - tim[i] * P1i;
    float P2i = trm[i] * P1i + tim[i] * P1r;
    float Qr = (P2r * denr + P2i * deni) * dinv;
    float Qi = (P2i * denr - P2r * deni) * dinv;
    atR[h * 4096 + m] = make_float2(S[i][0] - Qr, S[i][1] - Qi);
  }
}

// ---------------- Kernel 1b: atRoots -> Khat (+D) ----------------
__global__ __launch_bounds__(256) void k_khat(const float2* __restrict__ atR,
                                              const float* __restrict__ Dp,
                                              float2* __restrict__ Khat) {
  __shared__ float2 lds[4368];
  const int h = blockIdx.x;
  const int tid = threadIdx.x;
  float2 v[16];
#pragma unroll
  for (int c = 0; c < 16; ++c) v[c] = atR[h * 4096 + tid + 256 * c];
  fft4096_regs<1>(v, lds, tid);  // unnormalized inverse -> zK
  const int kb = (tid >> 4) + 16 * (tid & 15);
  float* ldsf = (float*)lds;
  const float s = 1.0f / 4096.0f;
  __syncthreads();
#pragma unroll
  for (int al = 0; al < 16; ++al) {
    int l = kb + 256 * al;
    ldsf[ad(l)] = v[al].x * s;  // K[l]
  }
  __syncthreads();
  // pack K[2n] + i K[2n+1], zero-pad
#pragma unroll
  for (int c = 0; c < 8; ++c) {
    int n = tid + 256 * c;
    v[c] = make_float2(ldsf[ad(2 * n)], ldsf[ad(2 * n + 1)]);
  }
#pragma unroll
  for (int c = 8; c < 16; ++c) v[c] = make_float2(0.f, 0.f);
  fft4096_regs<-1>(v, lds, tid);  // forward
  __syncthreads();
#pragma unroll
  for (int al = 0; al < 16; ++al) {
    int k = kb + 256 * al;
    lds[ad(k)] = v[al];
  }
  __syncthreads();
  const float Dh = Dp[h];
  float2* Kr = Khat + h * 4097;
  for (int k = tid; k <= 2048; k += 256) {
    float2 Zk = lds[ad(k)];
    float2 Zm = lds[ad((4096 - k) & 4095)];
    float Er = 0.5f * (Zk.x + Zm.x), Ei = 0.5f * (Zk.y - Zm.y);
    float Or = 0.5f * (Zk.y + Zm.y), Oi = 0.5f * (Zm.x - Zk.x);
    float swn, cwn;
    __sincosf(-(PI_F / 4096.0f) * (float)k, &swn, &cwn);
    float WOr = cwn * Or - swn * Oi, WOi = cwn * Oi + swn * Or;
    Kr[k] = make_float2(Er + WOr + Dh, Ei + WOi);  // + D (DC delta)
    if (k != 2048) Kr[4096 - k] = make_float2(Er - WOr + Dh, WOi - Ei);
  }
}

// ---------------- Kernel 2: per-row FFT convolution ----------------
__global__ __launch_bounds__(256) void k_conv(const float* __restrict__ u,
                                              const float2* __restrict__ Khat,
                                              float* __restrict__ y) {
  __shared__ float2 lds[4368];
  const int r = blockIdx.x;  // b*128 + h
  const int h = r & 127;
  const int tid = threadIdx.x;
  const float2* u2 = (const float2*)(u + (size_t)r * 4096);
  float2 v[16];
#pragma unroll
  for (int c = 0; c < 8; ++c) v[c] = u2[tid + 256 * c];
#pragma unroll
  for (int c = 8; c < 16; ++c) v[c] = make_float2(0.f, 0.f);
  fft4096_regs<-1>(v, lds, tid);  // forward; v[al]=Z[kb+256al]
  const int kb = (tid >> 4) + 16 * (tid & 15);
  __syncthreads();
#pragma unroll
  for (int al = 0; al < 16; ++al) {
    int k = kb + 256 * al;
    lds[ad(k)] = v[al];
  }
  __syncthreads();
  // spectral multiply, in-place pairwise (each (k,4096-k) owned by one thread)
  const float2* __restrict__ Kr = Khat + h * 4097;
  const float s = 1.0f / 4096.0f;
  for (int k = tid; k <= 2048; k += 256) {
    float2 Zk = lds[ad(k)];
    float2 Zm = lds[ad((4096 - k) & 4095)];
    float Er = 0.5f * (Zk.x + Zm.x), Ei = 0.5f * (Zk.y - Zm.y);
    float Or = 0.5f * (Zk.y + Zm.y), Oi = 0.5f * (Zm.x - Zk.x);
    float swn, cwn;
    __sincosf(-(PI_F / 4096.0f) * (float)k, &swn, &cwn);
    float WOr = cwn * Or - swn * Oi, WOi = cwn * Oi + swn * Or;
    float U1r = Er + WOr, U1i = Ei + WOi;
    float U2r = Er - WOr, U2i = WOi - Ei;
    float2 K1 = Kr[k], K2 = Kr[4096 - k];
    float Y1r = U1r * K1.x - U1i * K1.y, Y1i = U1r * K1.y + U1i * K1.x;
    float Y2r = U2r * K2.x - U2i * K2.y, Y2i = U2r * K2.y + U2i * K2.x;
    float Epr = 0.5f * (Y1r + Y2r), Epi = 0.5f * (Y1i - Y2i);
    float Tr = 0.5f * (Y1r - Y2r), Ti = 0.5f * (Y1i + Y2i);
    float O2r = cwn * Tr + swn * Ti, O2i = cwn * Ti - swn * Tr;
    lds[ad(k)] = make_float2((Epr - O2i) * s, (Epi + O2r) * s);
    if (k != 0 && k != 2048)
      lds[ad(4096 - k)] = make_float2((Epr + O2i) * s, (O2r - Epi) * s);
  }
  __syncthreads();
#pragma unroll
  for (int c = 0; c < 16; ++c) {
    int j = tid + 256 * c;
    v[c] = lds[ad(j)];
  }
  fft4096_regs<1>(v, lds, tid);  // inverse (scale folded); zy packed
  __syncthreads();
#pragma unroll
  for (int al = 0; al < 8; ++al) {  // only n<2048 needed (first L outputs)
    int k = kb + 256 * al;
    lds[ad(k)] = v[al];
  }
  __syncthreads();
  float4* y4 = (float4*)(y + (size_t)r * 4096);
#pragma unroll
  for (int i = 0; i < 4; ++i) {
    int j4 = tid + 256 * i;
    float2 z0 = lds[ad(2 * j4)];
    float2 z1 = lds[ad(2 * j4 + 1)];
    y4[j4] = make_float4(z0.x, z0.y, z1.x, z1.y);
  }
}

extern "C" void kernel_launch(void* const* d_in, const int* in_sizes, int n_in,
                              void* d_out, int out_size, void* d_ws,
                              size_t ws_size, hipStream_t stream) {
  (void)in_sizes; (void)n_in; (void)out_size; (void)ws_size;
  const float* u = (const float*)d_in[0];
  const float* Lre = (const float*)d_in[1];
  const float* Lim = (const float*)d_in[2];
  const float* Pri = (const float*)d_in[3];
  const float* Bri = (const float*)d_in[4];
  const float* Cri = (const float*)d_in[5];
  const float* lst = (const float*)d_in[6];
  const float* Dp = (const float*)d_in[7];
  float* y = (float*)d_out;
  float2* atR = (float2*)d_ws;
  float2* Khat = (float2*)((char*)d_ws + (size_t)128 * 4096 * sizeof(float2));

  k_cauchy<<<512, 256, 0, stream>>>(Lre, Lim, Pri, Bri, Cri, lst, atR);
  k_khat<<<128, 256, 0, stream>>>(atR, Dp, Khat);
  k_conv<<<2048, 256, 0, stream>>>(u, Khat, y);
}